// Round 1
// baseline (10430.996 us; speedup 1.0000x reference)
//
#include <hip/hip_runtime.h>
#include <math.h>

// Padded row stride for all node-feature buffers (max dim 24, multiple of 4
// so rows are 16B aligned for float4 access).
static constexpr int ST = 24;

__global__ void k_init_deg(float* __restrict__ deg, int n) {
    int v = blockIdx.x * blockDim.x + threadIdx.x;
    if (v < n) deg[v] = 1.0f;  // self-loop
}

__global__ void k_count_deg(const int* __restrict__ dst, float* __restrict__ deg, int ne) {
    int e = blockIdx.x * blockDim.x + threadIdx.x;
    if (e < ne) atomicAdd(&deg[dst[e]], 1.0f);
}

__global__ void k_dinv(float* __restrict__ deg, int n) {
    int v = blockIdx.x * blockDim.x + threadIdx.x;
    if (v < n) deg[v] = rsqrtf(deg[v]);  // deg >= 1 always (self-loop)
}

// g[v][j] = dinv[v] * sum_i h[v][i] * W[i][j]   (j < DOUT; pad cols zeroed)
template<int DIN, int DOUT>
__global__ void k_nodelinear(const float* __restrict__ h, int hstride,
                             const float* __restrict__ W,
                             const float* __restrict__ dinv,
                             float* __restrict__ g, int n) {
    int t = blockIdx.x * blockDim.x + threadIdx.x;
    int v = t / ST, j = t % ST;
    if (v >= n) return;
    float a = 0.0f;
    if (j < DOUT) {
        const float* hr = h + (size_t)v * hstride;
        #pragma unroll
        for (int i = 0; i < DIN; ++i) a += hr[i] * W[i * DOUT + j];
        a *= dinv[v];
    }
    g[(size_t)v * ST + j] = a;
}

// acc[dst] += g[src]  (per-edge scatter with float atomics)
template<int DOUT>
__global__ void k_scatter(const int* __restrict__ src, const int* __restrict__ dst,
                          const float* __restrict__ g, float* __restrict__ acc, int ne) {
    int e = blockIdx.x * blockDim.x + threadIdx.x;
    if (e >= ne) return;
    int s = src[e], d = dst[e];
    float vals[ST];
    const float4* g4 = reinterpret_cast<const float4*>(g + (size_t)s * ST);
    #pragma unroll
    for (int k = 0; k < ST / 4; ++k) reinterpret_cast<float4*>(vals)[k] = g4[k];
    float* ar = acc + (size_t)d * ST;
    #pragma unroll
    for (int f = 0; f < DOUT; ++f) atomicAdd(&ar[f], vals[f]);
}

// hout[v][f] = tanh(dinv[v]*(acc[v][f] + g[v][f]) + b[f])   (pad -> 0)
template<int DOUT>
__global__ void k_finish(const float* __restrict__ acc, const float* __restrict__ g,
                         const float* __restrict__ dinv, const float* __restrict__ b,
                         float* __restrict__ hout, int n) {
    int t = blockIdx.x * blockDim.x + threadIdx.x;
    int v = t / ST, f = t % ST;
    if (v >= n) return;
    float r = 0.0f;
    if (f < DOUT) r = tanhf(dinv[v] * (acc[(size_t)v * ST + f] + g[(size_t)v * ST + f]) + b[f]);
    hout[(size_t)v * ST + f] = r;
}

// Dense MLP: 20 -> 24 -> 18 -> 12, tanh each layer. One thread per node.
__global__ void k_mlp(const float* __restrict__ h,  // stride ST, dim 20
                      const float* __restrict__ L1w, const float* __restrict__ L1b,
                      const float* __restrict__ L2w, const float* __restrict__ L2b,
                      const float* __restrict__ L3w, const float* __restrict__ L3b,
                      float* __restrict__ hf, int n) {
    int v = blockIdx.x * blockDim.x + threadIdx.x;
    if (v >= n) return;
    float a0[20], a1[24], a2[18], a3[12];
    const float* hr = h + (size_t)v * ST;
    #pragma unroll
    for (int i = 0; i < 20; ++i) a0[i] = hr[i];
    #pragma unroll
    for (int j = 0; j < 24; ++j) {
        float s = L1b[j];
        #pragma unroll
        for (int i = 0; i < 20; ++i) s += a0[i] * L1w[i * 24 + j];
        a1[j] = tanhf(s);
    }
    #pragma unroll
    for (int j = 0; j < 18; ++j) {
        float s = L2b[j];
        #pragma unroll
        for (int i = 0; i < 24; ++i) s += a1[i] * L2w[i * 18 + j];
        a2[j] = tanhf(s);
    }
    #pragma unroll
    for (int j = 0; j < 12; ++j) {
        float s = L3b[j];
        #pragma unroll
        for (int i = 0; i < 18; ++i) s += a2[i] * L3w[i * 12 + j];
        a3[j] = tanhf(s);
    }
    float4* o = reinterpret_cast<float4*>(hf + (size_t)v * 12);
    o[0] = make_float4(a3[0], a3[1], a3[2], a3[3]);
    o[1] = make_float4(a3[4], a3[5], a3[6], a3[7]);
    o[2] = make_float4(a3[8], a3[9], a3[10], a3[11]);
}

// Per edge: e_row = [hf[src], hf[dst]] (24); out = e_row @ Cw + Cb (3).
__global__ void k_edge(const int* __restrict__ src, const int* __restrict__ dst,
                       const float* __restrict__ hf,
                       const float* __restrict__ Cw, const float* __restrict__ Cb,
                       float* __restrict__ out, float* __restrict__ eout, int ne) {
    int e = blockIdx.x * blockDim.x + threadIdx.x;
    if (e >= ne) return;
    int s = src[e], d = dst[e];
    float v[24];
    const float4* hs4 = reinterpret_cast<const float4*>(hf + (size_t)s * 12);
    const float4* hd4 = reinterpret_cast<const float4*>(hf + (size_t)d * 12);
    #pragma unroll
    for (int k = 0; k < 3; ++k) reinterpret_cast<float4*>(v)[k] = hs4[k];
    #pragma unroll
    for (int k = 0; k < 3; ++k) reinterpret_cast<float4*>(v + 12)[k] = hd4[k];

    float o0 = Cb[0], o1 = Cb[1], o2 = Cb[2];
    #pragma unroll
    for (int k = 0; k < 24; ++k) {
        o0 += v[k] * Cw[k * 3 + 0];
        o1 += v[k] * Cw[k * 3 + 1];
        o2 += v[k] * Cw[k * 3 + 2];
    }
    float* op = out + (size_t)e * 3;
    op[0] = o0; op[1] = o1; op[2] = o2;

    float4* ep = reinterpret_cast<float4*>(eout + (size_t)e * 24);
    #pragma unroll
    for (int k = 0; k < 6; ++k) ep[k] = reinterpret_cast<const float4*>(v)[k];
}

extern "C" void kernel_launch(void* const* d_in, const int* in_sizes, int n_in,
                              void* d_out, int out_size, void* d_ws, size_t ws_size,
                              hipStream_t stream) {
    const float* x  = (const float*)d_in[0];
    const int*   ei = (const int*)d_in[1];
    const int n  = in_sizes[2];        // batch has N entries
    const int ne = in_sizes[1] / 2;
    const int F  = in_sizes[0] / n;    // 10
    const int* src = ei;
    const int* dstp = ei + ne;

    const float *W1 = (const float*)d_in[3],  *b1 = (const float*)d_in[4];
    const float *W2 = (const float*)d_in[5],  *b2 = (const float*)d_in[6];
    const float *W3 = (const float*)d_in[7],  *b3 = (const float*)d_in[8];
    const float *L1w = (const float*)d_in[9],  *L1b = (const float*)d_in[10];
    const float *L2w = (const float*)d_in[11], *L2b = (const float*)d_in[12];
    const float *L3w = (const float*)d_in[13], *L3b = (const float*)d_in[14];
    const float *Cw  = (const float*)d_in[15], *Cb  = (const float*)d_in[16];

    float* ws  = (float*)d_ws;
    float* deg = ws;                         // n floats (becomes dinv in place)
    float* g   = deg + n;                    // n*ST
    float* acc = g + (size_t)n * ST;         // n*ST
    float* h1  = acc + (size_t)n * ST;       // n*ST
    float* h2  = h1 + (size_t)n * ST;        // n*ST
    float* hf  = h2 + (size_t)n * ST;        // n*12

    const int B = 256;
    const int gb_n   = (n + B - 1) / B;
    const int gb_n24 = (n * ST + B - 1) / B;
    const int gb_e   = (ne + B - 1) / B;

    // degree / dinv
    k_init_deg<<<gb_n, B, 0, stream>>>(deg, n);
    k_count_deg<<<gb_e, B, 0, stream>>>(dstp, deg, ne);
    k_dinv<<<gb_n, B, 0, stream>>>(deg, n);

    // conv1: F(10) -> 18
    k_nodelinear<10, 18><<<gb_n24, B, 0, stream>>>(x, F, W1, deg, g, n);
    hipMemsetAsync(acc, 0, (size_t)n * ST * sizeof(float), stream);
    k_scatter<18><<<gb_e, B, 0, stream>>>(src, dstp, g, acc, ne);
    k_finish<18><<<gb_n24, B, 0, stream>>>(acc, g, deg, b1, h1, n);

    // conv2: 18 -> 24
    k_nodelinear<18, 24><<<gb_n24, B, 0, stream>>>(h1, ST, W2, deg, g, n);
    hipMemsetAsync(acc, 0, (size_t)n * ST * sizeof(float), stream);
    k_scatter<24><<<gb_e, B, 0, stream>>>(src, dstp, g, acc, ne);
    k_finish<24><<<gb_n24, B, 0, stream>>>(acc, g, deg, b2, h2, n);

    // conv3: 24 -> 20
    k_nodelinear<24, 20><<<gb_n24, B, 0, stream>>>(h2, ST, W3, deg, g, n);
    hipMemsetAsync(acc, 0, (size_t)n * ST * sizeof(float), stream);
    k_scatter<20><<<gb_e, B, 0, stream>>>(src, dstp, g, acc, ne);
    k_finish<20><<<gb_n24, B, 0, stream>>>(acc, g, deg, b3, h1, n);

    // MLP 20 -> 24 -> 18 -> 12
    k_mlp<<<gb_n, B, 0, stream>>>(h1, L1w, L1b, L2w, L2b, L3w, L3b, hf, n);

    // edge head: out [E,3] then e [E,24], concatenated in d_out
    float* out_p = (float*)d_out;
    float* e_p   = out_p + (size_t)ne * 3;
    k_edge<<<gb_e, B, 0, stream>>>(src, dstp, hf, Cw, Cb, out_p, e_p, ne);
}

// Round 2
// 1375.338 us; speedup vs baseline: 7.5843x; 7.5843x over previous
//
#include <hip/hip_runtime.h>
#include <math.h>

// Node-feature row stride: 32 floats = 128 B (cacheline-aligned rows).
static constexpr int ST = 32;

// ---- CSR build --------------------------------------------------------------

__global__ void k_hist(const int* __restrict__ dst, int* __restrict__ count, int ne) {
    int e = blockIdx.x * blockDim.x + threadIdx.x;
    if (e < ne) atomicAdd(&count[dst[e]], 1);
}

// One block, 1024 threads: exclusive scan of count -> row_start/cursor, and
// dinv[v] = rsqrt(count[v] + 1)  (self-loop included).
__global__ void k_scan(const int* __restrict__ count, int* __restrict__ row_start,
                       int* __restrict__ cursor, float* __restrict__ dinv, int n) {
    __shared__ int partial[1024];
    int tid = threadIdx.x;
    int chunk = (n + 1023) / 1024;
    int beg = tid * chunk, end = min(beg + chunk, n);
    int s = 0;
    for (int i = beg; i < end; ++i) s += count[i];
    partial[tid] = s;
    __syncthreads();
    for (int off = 1; off < 1024; off <<= 1) {
        int val = (tid >= off) ? partial[tid - off] : 0;
        __syncthreads();
        partial[tid] += val;
        __syncthreads();
    }
    int run = (tid == 0) ? 0 : partial[tid - 1];
    for (int i = beg; i < end; ++i) {
        int c = count[i];
        row_start[i] = run;
        cursor[i] = run;
        dinv[i] = rsqrtf((float)(c + 1));
        run += c;
    }
    if (tid == 1023) row_start[n] = run;
}

__global__ void k_fill(const int* __restrict__ src, const int* __restrict__ dst,
                       int* __restrict__ cursor, int* __restrict__ csr_src, int ne) {
    int e = blockIdx.x * blockDim.x + threadIdx.x;
    if (e >= ne) return;
    int pos = atomicAdd(&cursor[dst[e]], 1);
    csr_src[pos] = src[e];
}

// ---- GCN conv pieces --------------------------------------------------------

// g[v][j] = dinv[v] * sum_i h[v][i] * W[i][j]   (j < DOUT; pad cols zeroed)
template<int DIN, int DOUT>
__global__ void k_nodelinear(const float* __restrict__ h, int hstride,
                             const float* __restrict__ W,
                             const float* __restrict__ dinv,
                             float* __restrict__ g, int n) {
    int t = blockIdx.x * blockDim.x + threadIdx.x;
    int v = t >> 5, j = t & 31;
    if (v >= n) return;
    float a = 0.0f;
    if (j < DOUT) {
        const float* hr = h + (size_t)v * hstride;
        #pragma unroll
        for (int i = 0; i < DIN; ++i) a += hr[i] * W[i * DOUT + j];
        a *= dinv[v];
    }
    g[(size_t)v * ST + j] = a;
}

// hout[v][f] = tanh(dinv[v] * (g[v][f] + sum_{e in CSR row v} g[src[e]][f]) + b[f])
template<int DOUT>
__global__ void k_gather_finish(const int* __restrict__ row_start,
                                const int* __restrict__ csr_src,
                                const float* __restrict__ g,
                                const float* __restrict__ dinv,
                                const float* __restrict__ b,
                                float* __restrict__ hout, int n) {
    int t = blockIdx.x * blockDim.x + threadIdx.x;
    int v = t >> 5, f = t & 31;
    if (v >= n) return;
    float r = 0.0f;
    if (f < DOUT) {
        int beg = row_start[v], end = row_start[v + 1];
        float a = g[(size_t)v * ST + f];          // self-loop term
        for (int e = beg; e < end; ++e) {
            int s = csr_src[e];
            a += g[(size_t)s * ST + f];
        }
        r = tanhf(dinv[v] * a + b[f]);
    }
    hout[(size_t)v * ST + f] = r;
}

// ---- Dense MLP: 20 -> 24 -> 18 -> 12, tanh each layer. One thread per node.
__global__ void k_mlp(const float* __restrict__ h,  // stride ST, dim 20
                      const float* __restrict__ L1w, const float* __restrict__ L1b,
                      const float* __restrict__ L2w, const float* __restrict__ L2b,
                      const float* __restrict__ L3w, const float* __restrict__ L3b,
                      float* __restrict__ hf, int n) {
    int v = blockIdx.x * blockDim.x + threadIdx.x;
    if (v >= n) return;
    float a0[20], a1[24], a2[18], a3[12];
    const float* hr = h + (size_t)v * ST;
    #pragma unroll
    for (int i = 0; i < 20; ++i) a0[i] = hr[i];
    #pragma unroll
    for (int j = 0; j < 24; ++j) {
        float s = L1b[j];
        #pragma unroll
        for (int i = 0; i < 20; ++i) s += a0[i] * L1w[i * 24 + j];
        a1[j] = tanhf(s);
    }
    #pragma unroll
    for (int j = 0; j < 18; ++j) {
        float s = L2b[j];
        #pragma unroll
        for (int i = 0; i < 24; ++i) s += a1[i] * L2w[i * 18 + j];
        a2[j] = tanhf(s);
    }
    #pragma unroll
    for (int j = 0; j < 12; ++j) {
        float s = L3b[j];
        #pragma unroll
        for (int i = 0; i < 18; ++i) s += a2[i] * L3w[i * 12 + j];
        a3[j] = tanhf(s);
    }
    float4* o = reinterpret_cast<float4*>(hf + (size_t)v * 12);
    o[0] = make_float4(a3[0], a3[1], a3[2], a3[3]);
    o[1] = make_float4(a3[4], a3[5], a3[6], a3[7]);
    o[2] = make_float4(a3[8], a3[9], a3[10], a3[11]);
}

// ---- Edge head: e_row = [hf[src], hf[dst]]; out = e_row @ Cw + Cb ----------
__global__ void k_edge(const int* __restrict__ src, const int* __restrict__ dst,
                       const float* __restrict__ hf,
                       const float* __restrict__ Cw, const float* __restrict__ Cb,
                       float* __restrict__ out, float* __restrict__ eout, int ne) {
    int e = blockIdx.x * blockDim.x + threadIdx.x;
    if (e >= ne) return;
    int s = src[e], d = dst[e];
    float v[24];
    const float4* hs4 = reinterpret_cast<const float4*>(hf + (size_t)s * 12);
    const float4* hd4 = reinterpret_cast<const float4*>(hf + (size_t)d * 12);
    #pragma unroll
    for (int k = 0; k < 3; ++k) reinterpret_cast<float4*>(v)[k] = hs4[k];
    #pragma unroll
    for (int k = 0; k < 3; ++k) reinterpret_cast<float4*>(v + 12)[k] = hd4[k];

    float o0 = Cb[0], o1 = Cb[1], o2 = Cb[2];
    #pragma unroll
    for (int k = 0; k < 24; ++k) {
        o0 += v[k] * Cw[k * 3 + 0];
        o1 += v[k] * Cw[k * 3 + 1];
        o2 += v[k] * Cw[k * 3 + 2];
    }
    float* op = out + (size_t)e * 3;
    op[0] = o0; op[1] = o1; op[2] = o2;

    float4* ep = reinterpret_cast<float4*>(eout + (size_t)e * 24);
    #pragma unroll
    for (int k = 0; k < 6; ++k) ep[k] = reinterpret_cast<const float4*>(v)[k];
}

extern "C" void kernel_launch(void* const* d_in, const int* in_sizes, int n_in,
                              void* d_out, int out_size, void* d_ws, size_t ws_size,
                              hipStream_t stream) {
    const float* x  = (const float*)d_in[0];
    const int*   ei = (const int*)d_in[1];
    const int n  = in_sizes[2];
    const int ne = in_sizes[1] / 2;
    const int F  = in_sizes[0] / n;    // 10
    const int* src  = ei;
    const int* dstp = ei + ne;

    const float *W1 = (const float*)d_in[3],  *b1 = (const float*)d_in[4];
    const float *W2 = (const float*)d_in[5],  *b2 = (const float*)d_in[6];
    const float *W3 = (const float*)d_in[7],  *b3 = (const float*)d_in[8];
    const float *L1w = (const float*)d_in[9],  *L1b = (const float*)d_in[10];
    const float *L2w = (const float*)d_in[11], *L2b = (const float*)d_in[12];
    const float *L3w = (const float*)d_in[13], *L3b = (const float*)d_in[14];
    const float *Cw  = (const float*)d_in[15], *Cb  = (const float*)d_in[16];

    // Workspace layout (16B-aligned vector buffers first).
    float* g   = (float*)d_ws;                 // n*ST
    float* h1  = g  + (size_t)n * ST;          // n*ST
    float* h2  = h1 + (size_t)n * ST;          // n*ST
    float* dinv = h2 + (size_t)n * ST;         // n
    int* count  = (int*)(dinv + n);            // n
    int* row    = count + n;                   // n+1
    int* cursor = row + (n + 1);               // n
    int* csr    = cursor + n;                  // ne
    float* hf   = g;                            // reuse g after conv3 (n*12)

    const int B = 256;
    const int gb_n   = (n + B - 1) / B;
    const int gb_n32 = (n * ST + B - 1) / B;
    const int gb_e   = (ne + B - 1) / B;

    // CSR build (per call; no state carried across calls)
    hipMemsetAsync(count, 0, (size_t)n * sizeof(int), stream);
    k_hist<<<gb_e, B, 0, stream>>>(dstp, count, ne);
    k_scan<<<1, 1024, 0, stream>>>(count, row, cursor, dinv, n);
    k_fill<<<gb_e, B, 0, stream>>>(src, dstp, cursor, csr, ne);

    // conv1: 10 -> 18
    k_nodelinear<10, 18><<<gb_n32, B, 0, stream>>>(x, F, W1, dinv, g, n);
    k_gather_finish<18><<<gb_n32, B, 0, stream>>>(row, csr, g, dinv, b1, h1, n);
    // conv2: 18 -> 24
    k_nodelinear<18, 24><<<gb_n32, B, 0, stream>>>(h1, ST, W2, dinv, g, n);
    k_gather_finish<24><<<gb_n32, B, 0, stream>>>(row, csr, g, dinv, b2, h2, n);
    // conv3: 24 -> 20
    k_nodelinear<24, 20><<<gb_n32, B, 0, stream>>>(h2, ST, W3, dinv, g, n);
    k_gather_finish<20><<<gb_n32, B, 0, stream>>>(row, csr, g, dinv, b3, h1, n);

    // MLP 20 -> 24 -> 18 -> 12
    k_mlp<<<gb_n, B, 0, stream>>>(h1, L1w, L1b, L2w, L2b, L3w, L3b, hf, n);

    // edge head: out [E,3] then e [E,24], concatenated flat in d_out
    float* out_p = (float*)d_out;
    float* e_p   = out_p + (size_t)ne * 3;
    k_edge<<<gb_e, B, 0, stream>>>(src, dstp, hf, Cw, Cb, out_p, e_p, ne);
}

// Round 3
// 908.031 us; speedup vs baseline: 11.4875x; 1.5146x over previous
//
#include <hip/hip_runtime.h>
#include <math.h>

// Node-feature row stride: 32 floats = 128 B (cacheline-aligned rows).
static constexpr int ST = 32;

// CSR build via LDS counting sort: bucket = dst >> BSHIFT.
static constexpr int BSHIFT = 7;            // 128 nodes per bucket
static constexpr int NB     = 1024;         // buckets (covers n < 131072)
static constexpr int NBLK   = 128;          // blocks for hist/partition passes

// ---- CSR build (no global atomics) -----------------------------------------

// Per-block LDS histogram of dst buckets; counts stored bucket-major:
// block_counts[b * NBLK + blk]
__global__ void k_p1_hist(const int* __restrict__ dst, int ne,
                          int* __restrict__ block_counts) {
    __shared__ int hist[NB];
    int blk = blockIdx.x, tid = threadIdx.x;
    for (int i = tid; i < NB; i += blockDim.x) hist[i] = 0;
    __syncthreads();
    int chunk = (ne + NBLK - 1) / NBLK;
    int beg = blk * chunk, end = min(beg + chunk, ne);
    for (int e = beg + tid; e < end; e += blockDim.x)
        atomicAdd(&hist[dst[e] >> BSHIFT], 1);
    __syncthreads();
    for (int b = tid; b < NB; b += blockDim.x)
        block_counts[b * NBLK + blk] = hist[b];
}

// Single block: exclusive scan (in place) of block_counts[NB*NBLK];
// emit bucket_base[NB+1] and row_start[n] = ne.
__global__ void k_p2_scan(int* __restrict__ bc, int* __restrict__ bucket_base,
                          int* __restrict__ row_start, int n, int ne) {
    __shared__ int partial[1024];
    const int M = NB * NBLK;
    int tid = threadIdx.x;
    int seg = M / 1024;                      // 128
    int beg = tid * seg, end = beg + seg;
    int s = 0;
    for (int i = beg; i < end; ++i) s += bc[i];
    partial[tid] = s;
    __syncthreads();
    for (int off = 1; off < 1024; off <<= 1) {
        int val = (tid >= off) ? partial[tid - off] : 0;
        __syncthreads();
        partial[tid] += val;
        __syncthreads();
    }
    int run = (tid == 0) ? 0 : partial[tid - 1];
    for (int i = beg; i < end; ++i) {
        int t = bc[i];
        bc[i] = run;
        run += t;
    }
    __syncthreads();
    for (int b = tid; b < NB; b += 1024) bucket_base[b] = bc[b * NBLK];
    if (tid == 0) { bucket_base[NB] = ne; row_start[n] = ne; }
}

// Re-read edges; place (src,dst) into bucket-partitioned edge_part using
// LDS cursors initialized from scanned block_counts.
__global__ void k_p3_partition(const int* __restrict__ src, const int* __restrict__ dst,
                               int ne, const int* __restrict__ bc,
                               int2* __restrict__ edge_part) {
    __shared__ int cur[NB];
    int blk = blockIdx.x, tid = threadIdx.x;
    for (int b = tid; b < NB; b += blockDim.x) cur[b] = bc[b * NBLK + blk];
    __syncthreads();
    int chunk = (ne + NBLK - 1) / NBLK;
    int beg = blk * chunk, end = min(beg + chunk, ne);
    for (int e = beg + tid; e < end; e += blockDim.x) {
        int d = dst[e];
        int pos = atomicAdd(&cur[d >> BSHIFT], 1);
        edge_part[pos] = make_int2(src[e], d);
    }
}

// One block per bucket: per-node counts (LDS), scan -> row_start/dinv/cursors,
// then place src into the bucket's contiguous csr region.
__global__ void k_p4_build(const int2* __restrict__ edge_part,
                           const int* __restrict__ bucket_base,
                           int* __restrict__ csr, int* __restrict__ row_start,
                           float* __restrict__ dinv, int n) {
    __shared__ int cnt[1 << BSHIFT];
    __shared__ int off[1 << BSHIFT];
    const int BSZ = 1 << BSHIFT;
    int b = blockIdx.x, tid = threadIdx.x;
    int node_base = b << BSHIFT;
    if (node_base >= n) return;
    int ebeg = bucket_base[b], eend = bucket_base[b + 1];
    for (int i = tid; i < BSZ; i += blockDim.x) cnt[i] = 0;
    __syncthreads();
    for (int e = ebeg + tid; e < eend; e += blockDim.x)
        atomicAdd(&cnt[edge_part[e].y & (BSZ - 1)], 1);
    __syncthreads();
    if (tid == 0) {                       // serial scan of 128 counters
        int run = 0;
        for (int i = 0; i < BSZ; ++i) { off[i] = run; run += cnt[i]; }
    }
    __syncthreads();
    int nb_cnt = min(BSZ, n - node_base);
    for (int i = tid; i < nb_cnt; i += blockDim.x) {
        row_start[node_base + i] = ebeg + off[i];
        dinv[node_base + i] = rsqrtf((float)(cnt[i] + 1));
    }
    // reuse cnt as cursors
    for (int i = tid; i < BSZ; i += blockDim.x) cnt[i] = off[i];
    __syncthreads();
    for (int e = ebeg + tid; e < eend; e += blockDim.x) {
        int2 p = edge_part[e];
        int loc = atomicAdd(&cnt[p.y & (BSZ - 1)], 1);
        csr[ebeg + loc] = p.x;
    }
}

// ---- GCN conv pieces --------------------------------------------------------

// g[v][j] = dinv[v] * sum_i h[v][i] * W[i][j]   (j < DOUT; pad cols zeroed)
template<int DIN, int DOUT>
__global__ void k_nodelinear(const float* __restrict__ h, int hstride,
                             const float* __restrict__ W,
                             const float* __restrict__ dinv,
                             float* __restrict__ g, int n) {
    int t = blockIdx.x * blockDim.x + threadIdx.x;
    int v = t >> 5, j = t & 31;
    if (v >= n) return;
    float a = 0.0f;
    if (j < DOUT) {
        const float* hr = h + (size_t)v * hstride;
        #pragma unroll
        for (int i = 0; i < DIN; ++i) a += hr[i] * W[i * DOUT + j];
        a *= dinv[v];
    }
    g[(size_t)v * ST + j] = a;
}

// hout[v][f] = tanh(dinv[v] * (g[v][f] + sum_{e in CSR row v} g[src[e]][f]) + b[f])
template<int DOUT>
__global__ void k_gather_finish(const int* __restrict__ row_start,
                                const int* __restrict__ csr_src,
                                const float* __restrict__ g,
                                const float* __restrict__ dinv,
                                const float* __restrict__ b,
                                float* __restrict__ hout, int n) {
    int t = blockIdx.x * blockDim.x + threadIdx.x;
    int v = t >> 5, f = t & 31;
    if (v >= n) return;
    float r = 0.0f;
    if (f < DOUT) {
        int beg = row_start[v], end = row_start[v + 1];
        float a = g[(size_t)v * ST + f];          // self-loop term
        for (int e = beg; e < end; ++e) {
            int s = csr_src[e];
            a += g[(size_t)s * ST + f];
        }
        r = tanhf(dinv[v] * a + b[f]);
    }
    hout[(size_t)v * ST + f] = r;
}

// ---- Dense MLP: 20 -> 24 -> 18 -> 12, tanh each layer. One thread per node.
__global__ void k_mlp(const float* __restrict__ h,  // stride ST, dim 20
                      const float* __restrict__ L1w, const float* __restrict__ L1b,
                      const float* __restrict__ L2w, const float* __restrict__ L2b,
                      const float* __restrict__ L3w, const float* __restrict__ L3b,
                      float* __restrict__ hf, int n) {
    int v = blockIdx.x * blockDim.x + threadIdx.x;
    if (v >= n) return;
    float a0[20], a1[24], a2[18], a3[12];
    const float* hr = h + (size_t)v * ST;
    #pragma unroll
    for (int i = 0; i < 20; ++i) a0[i] = hr[i];
    #pragma unroll
    for (int j = 0; j < 24; ++j) {
        float s = L1b[j];
        #pragma unroll
        for (int i = 0; i < 20; ++i) s += a0[i] * L1w[i * 24 + j];
        a1[j] = tanhf(s);
    }
    #pragma unroll
    for (int j = 0; j < 18; ++j) {
        float s = L2b[j];
        #pragma unroll
        for (int i = 0; i < 24; ++i) s += a1[i] * L2w[i * 18 + j];
        a2[j] = tanhf(s);
    }
    #pragma unroll
    for (int j = 0; j < 12; ++j) {
        float s = L3b[j];
        #pragma unroll
        for (int i = 0; i < 18; ++i) s += a2[i] * L3w[i * 12 + j];
        a3[j] = tanhf(s);
    }
    float4* o = reinterpret_cast<float4*>(hf + (size_t)v * 12);
    o[0] = make_float4(a3[0], a3[1], a3[2], a3[3]);
    o[1] = make_float4(a3[4], a3[5], a3[6], a3[7]);
    o[2] = make_float4(a3[8], a3[9], a3[10], a3[11]);
}

// ---- Edge head: e_row = [hf[src], hf[dst]]; out = e_row @ Cw + Cb ----------
__global__ void k_edge(const int* __restrict__ src, const int* __restrict__ dst,
                       const float* __restrict__ hf,
                       const float* __restrict__ Cw, const float* __restrict__ Cb,
                       float* __restrict__ out, float* __restrict__ eout, int ne) {
    int e = blockIdx.x * blockDim.x + threadIdx.x;
    if (e >= ne) return;
    int s = src[e], d = dst[e];
    float v[24];
    const float4* hs4 = reinterpret_cast<const float4*>(hf + (size_t)s * 12);
    const float4* hd4 = reinterpret_cast<const float4*>(hf + (size_t)d * 12);
    #pragma unroll
    for (int k = 0; k < 3; ++k) reinterpret_cast<float4*>(v)[k] = hs4[k];
    #pragma unroll
    for (int k = 0; k < 3; ++k) reinterpret_cast<float4*>(v + 12)[k] = hd4[k];

    float o0 = Cb[0], o1 = Cb[1], o2 = Cb[2];
    #pragma unroll
    for (int k = 0; k < 24; ++k) {
        o0 += v[k] * Cw[k * 3 + 0];
        o1 += v[k] * Cw[k * 3 + 1];
        o2 += v[k] * Cw[k * 3 + 2];
    }
    float* op = out + (size_t)e * 3;
    op[0] = o0; op[1] = o1; op[2] = o2;

    float4* ep = reinterpret_cast<float4*>(eout + (size_t)e * 24);
    #pragma unroll
    for (int k = 0; k < 6; ++k) ep[k] = reinterpret_cast<const float4*>(v)[k];
}

extern "C" void kernel_launch(void* const* d_in, const int* in_sizes, int n_in,
                              void* d_out, int out_size, void* d_ws, size_t ws_size,
                              hipStream_t stream) {
    const float* x  = (const float*)d_in[0];
    const int*   ei = (const int*)d_in[1];
    const int n  = in_sizes[2];
    const int ne = in_sizes[1] / 2;
    const int F  = in_sizes[0] / n;    // 10
    const int* src  = ei;
    const int* dstp = ei + ne;

    const float *W1 = (const float*)d_in[3],  *b1 = (const float*)d_in[4];
    const float *W2 = (const float*)d_in[5],  *b2 = (const float*)d_in[6];
    const float *W3 = (const float*)d_in[7],  *b3 = (const float*)d_in[8];
    const float *L1w = (const float*)d_in[9],  *L1b = (const float*)d_in[10];
    const float *L2w = (const float*)d_in[11], *L2b = (const float*)d_in[12];
    const float *L3w = (const float*)d_in[13], *L3b = (const float*)d_in[14];
    const float *Cw  = (const float*)d_in[15], *Cb  = (const float*)d_in[16];

    // Workspace layout (all 16B aligned; edge_part aliases h1+h2).
    int* csr = (int*)d_ws;                         // ne
    int* row = csr + ne;                           // n+1 (pad to +4)
    float* dinv = (float*)(row + n + 4);           // n
    int* bucket_base = (int*)(dinv + n);           // NB+1 (pad to +4)
    int* block_counts = bucket_base + NB + 4;      // NB*NBLK
    float* g  = (float*)(block_counts + NB * NBLK);// n*ST
    float* h1 = g  + (size_t)n * ST;               // n*ST
    float* h2 = h1 + (size_t)n * ST;               // n*ST
    int2* edge_part = (int2*)h1;                   // ne int2 (25.6MB <= h1+h2)
    float* hf = g;                                 // n*12, reuse after conv3

    const int B = 256;
    const int gb_n   = (n + B - 1) / B;
    const int gb_n32 = (n * ST + B - 1) / B;
    const int gb_e   = (ne + B - 1) / B;

    // CSR build: LDS counting sort, no global atomics
    k_p1_hist<<<NBLK, B, 0, stream>>>(dstp, ne, block_counts);
    k_p2_scan<<<1, 1024, 0, stream>>>(block_counts, bucket_base, row, n, ne);
    k_p3_partition<<<NBLK, B, 0, stream>>>(src, dstp, ne, block_counts, edge_part);
    k_p4_build<<<NB, B, 0, stream>>>(edge_part, bucket_base, csr, row, dinv, n);

    // conv1: 10 -> 18
    k_nodelinear<10, 18><<<gb_n32, B, 0, stream>>>(x, F, W1, dinv, g, n);
    k_gather_finish<18><<<gb_n32, B, 0, stream>>>(row, csr, g, dinv, b1, h1, n);
    // conv2: 18 -> 24
    k_nodelinear<18, 24><<<gb_n32, B, 0, stream>>>(h1, ST, W2, dinv, g, n);
    k_gather_finish<24><<<gb_n32, B, 0, stream>>>(row, csr, g, dinv, b2, h2, n);
    // conv3: 24 -> 20
    k_nodelinear<24, 20><<<gb_n32, B, 0, stream>>>(h2, ST, W3, dinv, g, n);
    k_gather_finish<20><<<gb_n32, B, 0, stream>>>(row, csr, g, dinv, b3, h1, n);

    // MLP 20 -> 24 -> 18 -> 12
    k_mlp<<<gb_n, B, 0, stream>>>(h1, L1w, L1b, L2w, L2b, L3w, L3b, hf, n);

    // edge head: out [E,3] then e [E,24], concatenated flat in d_out
    float* out_p = (float*)d_out;
    float* e_p   = out_p + (size_t)ne * 3;
    k_edge<<<gb_e, B, 0, stream>>>(src, dstp, hf, Cw, Cb, out_p, e_p, ne);
}

// Round 4
// 788.930 us; speedup vs baseline: 13.2217x; 1.1510x over previous
//
#include <hip/hip_runtime.h>
#include <hip/hip_fp16.h>
#include <math.h>

static constexpr int ST   = 32;   // halfs per g-row  (64 B rows)
static constexpr int HFST = 16;   // floats per hf-row (64 B rows)

// CSR build via LDS counting sort: bucket = dst >> BSHIFT.
static constexpr int BSHIFT = 7;            // 128 nodes per bucket
static constexpr int NB     = 1024;         // buckets (covers n < 131072)
static constexpr int NBLK   = 128;          // blocks for hist/partition passes

// ---- CSR build (no global atomics) -----------------------------------------

__global__ void k_p1_hist(const int* __restrict__ dst, int ne,
                          int* __restrict__ bc) {
    __shared__ int hist[NB];
    int blk = blockIdx.x, tid = threadIdx.x;
    for (int i = tid; i < NB; i += blockDim.x) hist[i] = 0;
    __syncthreads();
    int chunk = (ne + NBLK - 1) / NBLK;
    int beg = blk * chunk, end = min(beg + chunk, ne);
    for (int e = beg + tid; e < end; e += blockDim.x)
        atomicAdd(&hist[dst[e] >> BSHIFT], 1);
    __syncthreads();
    for (int b = tid; b < NB; b += blockDim.x)
        bc[b * NBLK + blk] = hist[b];
}

// Single block: exclusive scan (in place) of bc[NB*NBLK]; emit bucket_base,
// row_start[n] = ne.
__global__ void k_p2_scan(int* __restrict__ bc, int* __restrict__ bucket_base,
                          int* __restrict__ row_start, int n, int ne) {
    __shared__ int partial[1024];
    const int M = NB * NBLK;
    int tid = threadIdx.x;
    int seg = M / 1024;
    int beg = tid * seg, end = beg + seg;
    int s = 0;
    for (int i = beg; i < end; ++i) s += bc[i];
    partial[tid] = s;
    __syncthreads();
    for (int off = 1; off < 1024; off <<= 1) {
        int val = (tid >= off) ? partial[tid - off] : 0;
        __syncthreads();
        partial[tid] += val;
        __syncthreads();
    }
    int run = (tid == 0) ? 0 : partial[tid - 1];
    for (int i = beg; i < end; ++i) {
        int t = bc[i];
        bc[i] = run;
        run += t;
    }
    __syncthreads();
    for (int b = tid; b < NB; b += 1024) bucket_base[b] = bc[b * NBLK];
    if (tid == 0) { bucket_base[NB] = ne; row_start[n] = ne; }
}

// Re-read edges; place packed (dlocal<<20 | src) into bucket-partitioned ep.
__global__ void k_p3_partition(const int* __restrict__ src, const int* __restrict__ dst,
                               int ne, const int* __restrict__ bc,
                               int* __restrict__ ep) {
    __shared__ int cur[NB];
    int blk = blockIdx.x, tid = threadIdx.x;
    for (int b = tid; b < NB; b += blockDim.x) cur[b] = bc[b * NBLK + blk];
    __syncthreads();
    int chunk = (ne + NBLK - 1) / NBLK;
    int beg = blk * chunk, end = min(beg + chunk, ne);
    for (int e = beg + tid; e < end; e += blockDim.x) {
        int d = dst[e];
        int pos = atomicAdd(&cur[d >> BSHIFT], 1);
        ep[pos] = src[e] | ((d & ((1 << BSHIFT) - 1)) << 20);
    }
}

// One block per bucket: per-node counts (LDS), scan -> row_start/dinv, then
// place src into the bucket's contiguous csr region.
__global__ void k_p4_build(const int* __restrict__ ep,
                           const int* __restrict__ bucket_base,
                           int* __restrict__ csr, int* __restrict__ row_start,
                           float* __restrict__ dinv, int n) {
    const int BSZ = 1 << BSHIFT;
    __shared__ int cnt[BSZ];
    __shared__ int off[BSZ];
    int b = blockIdx.x, tid = threadIdx.x;
    int node_base = b << BSHIFT;
    if (node_base >= n) return;
    int ebeg = bucket_base[b], eend = bucket_base[b + 1];
    for (int i = tid; i < BSZ; i += blockDim.x) cnt[i] = 0;
    __syncthreads();
    for (int e = ebeg + tid; e < eend; e += blockDim.x)
        atomicAdd(&cnt[ep[e] >> 20], 1);
    __syncthreads();
    if (tid == 0) {
        int run = 0;
        for (int i = 0; i < BSZ; ++i) { off[i] = run; run += cnt[i]; }
    }
    __syncthreads();
    int nb_cnt = min(BSZ, n - node_base);
    for (int i = tid; i < nb_cnt; i += blockDim.x) {
        row_start[node_base + i] = ebeg + off[i];
        dinv[node_base + i] = rsqrtf((float)(cnt[i] + 1));
    }
    for (int i = tid; i < BSZ; i += blockDim.x) cnt[i] = off[i];
    __syncthreads();
    for (int e = ebeg + tid; e < eend; e += blockDim.x) {
        int p = ep[e];
        int loc = atomicAdd(&cnt[p >> 20], 1);
        csr[ebeg + loc] = p & 0xFFFFF;
    }
}

// ---- conv1 node-linear: g1 = fp16( dinv[v] * (x @ W1) ) --------------------
__global__ void k_nl1(const float* __restrict__ x, int xs,
                      const float* __restrict__ W, const float* __restrict__ dinv,
                      __half* __restrict__ g, int n) {
    int t = blockIdx.x * blockDim.x + threadIdx.x;
    int v = t >> 5, j = t & 31;
    if (v >= n) return;
    float a = 0.0f;
    if (j < 18) {
        const float* xr = x + (size_t)v * xs;
        #pragma unroll
        for (int i = 0; i < 10; ++i) a += xr[i] * W[i * 18 + j];
        a *= dinv[v];
    }
    g[(size_t)v * ST + j] = __float2half(a);
}

// ---- fused: gather-finish(conv DP) + node-linear(DP->DN) -------------------
// h = tanh(dinv*(g_v + sum g_src) + b);  gout = fp16(dinv * (h @ W))
template<int DP, int DN>
__global__ void k_gfnl(const int* __restrict__ row, const int* __restrict__ csr,
                       const __half* __restrict__ gin, const float* __restrict__ dinv,
                       const float* __restrict__ bias, const float* __restrict__ W,
                       __half* __restrict__ gout, int n) {
    __shared__ float h_lds[8][ST];
    int t = blockIdx.x * 256 + threadIdx.x;
    int v = t >> 5, f = t & 31, ln = threadIdx.x >> 5;
    float dv = 0.0f, r = 0.0f;
    if (v < n) {
        dv = dinv[v];
        if (f < DP) {
            int beg = row[v], end = row[v + 1];
            float a = __half2float(gin[(size_t)v * ST + f]);
            for (int e = beg; e < end; ++e)
                a += __half2float(gin[(size_t)csr[e] * ST + f]);
            r = tanhf(dv * a + bias[f]);
        }
    }
    h_lds[ln][f] = r;
    __syncthreads();
    if (v < n) {
        float a = 0.0f;
        if (f < DN) {
            #pragma unroll
            for (int i = 0; i < DP; ++i) a += h_lds[ln][i] * W[i * DN + f];
            a *= dv;
        }
        gout[(size_t)v * ST + f] = __float2half(a);
    }
}

// ---- fused: gather-finish(conv3, DP=20) + MLP 20->24->18->12 ---------------
__global__ void k_gfmlp(const int* __restrict__ row, const int* __restrict__ csr,
                        const __half* __restrict__ gin, const float* __restrict__ dinv,
                        const float* __restrict__ b3,
                        const float* __restrict__ L1w, const float* __restrict__ L1b,
                        const float* __restrict__ L2w, const float* __restrict__ L2b,
                        const float* __restrict__ L3w, const float* __restrict__ L3b,
                        float* __restrict__ hf, int n) {
    __shared__ float A[8][ST];
    __shared__ float Bx[8][ST];
    int t = blockIdx.x * 256 + threadIdx.x;
    int v = t >> 5, f = t & 31, ln = threadIdx.x >> 5;
    float r = 0.0f;
    if (v < n && f < 20) {
        int beg = row[v], end = row[v + 1];
        float a = __half2float(gin[(size_t)v * ST + f]);
        for (int e = beg; e < end; ++e)
            a += __half2float(gin[(size_t)csr[e] * ST + f]);
        r = tanhf(dinv[v] * a + b3[f]);
    }
    A[ln][f] = r;
    __syncthreads();
    float s1 = 0.0f;
    if (v < n && f < 24) {
        float s = L1b[f];
        #pragma unroll
        for (int i = 0; i < 20; ++i) s += A[ln][i] * L1w[i * 24 + f];
        s1 = tanhf(s);
    }
    Bx[ln][f] = s1;
    __syncthreads();
    float s2 = 0.0f;
    if (v < n && f < 18) {
        float s = L2b[f];
        #pragma unroll
        for (int i = 0; i < 24; ++i) s += Bx[ln][i] * L2w[i * 18 + f];
        s2 = tanhf(s);
    }
    A[ln][f] = s2;
    __syncthreads();
    if (v < n && f < HFST) {
        float o = 0.0f;
        if (f < 12) {
            float s = L3b[f];
            #pragma unroll
            for (int i = 0; i < 18; ++i) s += A[ln][i] * L3w[i * 12 + f];
            o = tanhf(s);
        }
        hf[(size_t)v * HFST + f] = o;
    }
}

// ---- Edge head: e_row = [hf[src], hf[dst]]; out = e_row @ Cw + Cb ----------
__global__ void k_edge(const int* __restrict__ src, const int* __restrict__ dst,
                       const float* __restrict__ hf,
                       const float* __restrict__ Cw, const float* __restrict__ Cb,
                       float* __restrict__ out, float* __restrict__ eout, int ne) {
    int e = blockIdx.x * blockDim.x + threadIdx.x;
    if (e >= ne) return;
    int s = src[e], d = dst[e];
    float v[24];
    const float4* hs4 = reinterpret_cast<const float4*>(hf + (size_t)s * HFST);
    const float4* hd4 = reinterpret_cast<const float4*>(hf + (size_t)d * HFST);
    #pragma unroll
    for (int k = 0; k < 3; ++k) reinterpret_cast<float4*>(v)[k] = hs4[k];
    #pragma unroll
    for (int k = 0; k < 3; ++k) reinterpret_cast<float4*>(v + 12)[k] = hd4[k];

    float o0 = Cb[0], o1 = Cb[1], o2 = Cb[2];
    #pragma unroll
    for (int k = 0; k < 24; ++k) {
        o0 += v[k] * Cw[k * 3 + 0];
        o1 += v[k] * Cw[k * 3 + 1];
        o2 += v[k] * Cw[k * 3 + 2];
    }
    float* op = out + (size_t)e * 3;
    op[0] = o0; op[1] = o1; op[2] = o2;

    float4* ep = reinterpret_cast<float4*>(eout + (size_t)e * 24);
    #pragma unroll
    for (int k = 0; k < 6; ++k) ep[k] = reinterpret_cast<const float4*>(v)[k];
}

static inline char* align64(char* p) {
    return (char*)(((uintptr_t)p + 63) & ~(uintptr_t)63);
}

extern "C" void kernel_launch(void* const* d_in, const int* in_sizes, int n_in,
                              void* d_out, int out_size, void* d_ws, size_t ws_size,
                              hipStream_t stream) {
    const float* x  = (const float*)d_in[0];
    const int*   ei = (const int*)d_in[1];
    const int n  = in_sizes[2];
    const int ne = in_sizes[1] / 2;
    const int F  = in_sizes[0] / n;    // 10
    const int* src  = ei;
    const int* dstp = ei + ne;

    const float *W1 = (const float*)d_in[3],  *b1 = (const float*)d_in[4];
    const float *W2 = (const float*)d_in[5],  *b2 = (const float*)d_in[6];
    const float *W3 = (const float*)d_in[7],  *b3 = (const float*)d_in[8];
    const float *L1w = (const float*)d_in[9],  *L1b = (const float*)d_in[10];
    const float *L2w = (const float*)d_in[11], *L2b = (const float*)d_in[12];
    const float *L3w = (const float*)d_in[13], *L3b = (const float*)d_in[14];
    const float *Cw  = (const float*)d_in[15], *Cb  = (const float*)d_in[16];

    // Workspace layout
    char* p = (char*)d_ws;
    int* csr = (int*)p;                    p += (size_t)ne * 4;
    int* epk = (int*)p;                    p += (size_t)ne * 4;
    int* bc  = (int*)p;                    p += (size_t)NB * NBLK * 4;
    int* row = (int*)p;                    p += ((size_t)n + 4) * 4;
    int* bucket_base = (int*)p;            p += ((size_t)NB + 4) * 4;
    float* dinv = (float*)p;               p += (size_t)n * 4;
    p = align64(p);
    __half* g1 = (__half*)p;               p += (size_t)n * ST * 2;
    p = align64(p);
    __half* g2 = (__half*)p;               p += (size_t)n * ST * 2;
    p = align64(p);
    float* hf = (float*)p;                 p += (size_t)n * HFST * 4;

    const int B = 256;
    const int gb_n32 = (n * 32 + B - 1) / B;
    const int gb_e   = (ne + B - 1) / B;

    // CSR build: LDS counting sort, no global atomics
    k_p1_hist<<<NBLK, 1024, 0, stream>>>(dstp, ne, bc);
    k_p2_scan<<<1, 1024, 0, stream>>>(bc, bucket_base, row, n, ne);
    k_p3_partition<<<NBLK, 1024, 0, stream>>>(src, dstp, ne, bc, epk);
    k_p4_build<<<NB, B, 0, stream>>>(epk, bucket_base, csr, row, dinv, n);

    // conv1 linear: g1 = fp16(dinv * (x @ W1))
    k_nl1<<<gb_n32, B, 0, stream>>>(x, F, W1, dinv, g1, n);
    // conv1 gather+finish fused with conv2 linear -> g2
    k_gfnl<18, 24><<<gb_n32, B, 0, stream>>>(row, csr, g1, dinv, b1, W2, g2, n);
    // conv2 gather+finish fused with conv3 linear -> g1
    k_gfnl<24, 20><<<gb_n32, B, 0, stream>>>(row, csr, g2, dinv, b2, W3, g1, n);
    // conv3 gather+finish fused with MLP -> hf
    k_gfmlp<<<gb_n32, B, 0, stream>>>(row, csr, g1, dinv, b3,
                                      L1w, L1b, L2w, L2b, L3w, L3b, hf, n);

    // edge head: out [E,3] then e [E,24], concatenated flat in d_out
    float* out_p = (float*)d_out;
    float* e_p   = out_p + (size_t)ne * 3;
    k_edge<<<gb_e, B, 0, stream>>>(src, dstp, hf, Cw, Cb, out_p, e_p, ne);
}